// Round 1
// baseline (319.776 us; speedup 1.0000x reference)
//
#include <hip/hip_runtime.h>
#include <hip/hip_bf16.h>

// LocallyConnected2d: x [64,32,64,64] f32, weight [1,64,32,62,62,9] f32
// out [64,64,62,62] f32.  Per (oh,ow): out[b,o] = sum_{i,k} x[b,i,oh+k/3,ow+k%3]*w[o,i,oh,ow,k]
//
// Strategy: lanes = o (64), wave = b-half. Weight per-lane in VGPRs (read once),
// x values are wave-uniform -> scalar loads (SGPR) feeding v_fmac's SGPR operand.
// No LDS in the main loop -> not LDS-BW bound. xT pre-transpose makes the 32
// b-values per (i,k) contiguous for s_load_dwordx16.

#define LOCS 3844      // 62*62
#define WSTRIDE_I 34596u   // 62*62*9
#define WSTRIDE_O 1107072u // 32*62*62*9
#define XM 131072u     // 32*64*64 (per-b elements of x)

__global__ void lc2d_transpose_x(const float* __restrict__ x, float* __restrict__ xT) {
    __shared__ float tile[64][65];
    const int m0 = blockIdx.x * 64;
    const int t = threadIdx.x;
    const int c = t & 63, q = t >> 6;   // q in 0..3
#pragma unroll
    for (int j = 0; j < 16; ++j) {
        const int b = q * 16 + j;
        tile[c][b] = x[(size_t)b * XM + (size_t)(m0 + c)];
    }
    __syncthreads();
#pragma unroll
    for (int j = 0; j < 16; ++j) {
        const int m = q * 16 + j;
        xT[(size_t)(m0 + m) * 64u + (size_t)c] = tile[m][c];
    }
}

// USE_XT=1: read x from transposed buffer (contiguous in b, s_load_dwordx16)
// USE_XT=0: read x directly (32 separate uniform scalar dword loads) — ws fallback
template <int USE_XT>
__global__ __launch_bounds__(128) void lc2d_main(const float* __restrict__ w,
                                                 const float* __restrict__ xsrc,
                                                 float* __restrict__ out) {
    // bijective XCD-chunk swizzle: nwg=3844 = 8*480 + 4  (q=480, r=4)
    const int bid = blockIdx.x;
    const int xcd = bid & 7, jj = bid >> 3;
    const int loc = (xcd < 4) ? (xcd * 481 + jj) : (1924 + (xcd - 4) * 480 + jj);
    const int oh = loc / 62;
    const int ow = loc - oh * 62;

    const int lane = threadIdx.x & 63;          // = o
    int b0 = (threadIdx.x >> 6) << 5;           // wave's b-half base (0 or 32)
    b0 = __builtin_amdgcn_readfirstlane(b0);    // force wave-uniform (SGPR)

    const float* wp = w + (size_t)lane * WSTRIDE_O + (size_t)loc * 9u;

    float acc[32];
#pragma unroll
    for (int b = 0; b < 32; ++b) acc[b] = 0.f;

    float wA[9], wB[9];
#pragma unroll
    for (int k = 0; k < 9; ++k) wA[k] = wp[k];

#pragma unroll 1
    for (int i = 0; i < 32; i += 2) {
        {   // prefetch weights for i+1
            const float* wpn = wp + (size_t)(i + 1) * WSTRIDE_I;
#pragma unroll
            for (int k = 0; k < 9; ++k) wB[k] = wpn[k];
        }
        // ---- compute channel i with wA ----
#pragma unroll
        for (int k = 0; k < 9; ++k) {
            const int ki = k / 3, kj = k % 3;
            const int m = i * 4096 + (oh + ki) * 64 + (ow + kj);  // uniform
            float xv[32];
            if (USE_XT) {
                const float* xs = xsrc + (size_t)m * 64u + (size_t)b0;
#pragma unroll
                for (int b = 0; b < 32; ++b) xv[b] = xs[b];
            } else {
#pragma unroll
                for (int b = 0; b < 32; ++b)
                    xv[b] = xsrc[(size_t)(b0 + b) * XM + (size_t)m];
            }
#pragma unroll
            for (int b = 0; b < 32; ++b) acc[b] = fmaf(wA[k], xv[b], acc[b]);
        }
        if (i + 2 < 32) {  // prefetch weights for i+2
            const float* wpn = wp + (size_t)(i + 2) * WSTRIDE_I;
#pragma unroll
            for (int k = 0; k < 9; ++k) wA[k] = wpn[k];
        }
        // ---- compute channel i+1 with wB ----
#pragma unroll
        for (int k = 0; k < 9; ++k) {
            const int ki = k / 3, kj = k % 3;
            const int m = (i + 1) * 4096 + (oh + ki) * 64 + (ow + kj);
            float xv[32];
            if (USE_XT) {
                const float* xs = xsrc + (size_t)m * 64u + (size_t)b0;
#pragma unroll
                for (int b = 0; b < 32; ++b) xv[b] = xs[b];
            } else {
#pragma unroll
                for (int b = 0; b < 32; ++b)
                    xv[b] = xsrc[(size_t)(b0 + b) * XM + (size_t)m];
            }
#pragma unroll
            for (int b = 0; b < 32; ++b) acc[b] = fmaf(wB[k], xv[b], acc[b]);
        }
    }

    // out[b][o][oh][ow], o = lane; scattered dword stores (stride 3844),
    // adjacent-loc blocks on same XCD merge lines in L2.
#pragma unroll
    for (int b = 0; b < 32; ++b) {
        out[(size_t)((b0 + b) * 64 + lane) * (size_t)LOCS + (size_t)loc] = acc[b];
    }
}

extern "C" void kernel_launch(void* const* d_in, const int* in_sizes, int n_in,
                              void* d_out, int out_size, void* d_ws, size_t ws_size,
                              hipStream_t stream) {
    const float* x = (const float*)d_in[0];   // 64*32*64*64
    const float* w = (const float*)d_in[1];   // 1*64*32*62*62*9
    float* out = (float*)d_out;               // 64*64*62*62

    const size_t xt_bytes = (size_t)XM * 64u * sizeof(float);  // 32 MiB
    if (ws_size >= xt_bytes) {
        float* xT = (float*)d_ws;
        lc2d_transpose_x<<<dim3(XM / 64), dim3(256), 0, stream>>>(x, xT);
        lc2d_main<1><<<dim3(LOCS), dim3(128), 0, stream>>>(w, xT, out);
    } else {
        lc2d_main<0><<<dim3(LOCS), dim3(128), 0, stream>>>(w, x, out);
    }
}